// Round 1
// baseline (339.376 us; speedup 1.0000x reference)
//
#include <hip/hip_runtime.h>
#include <math.h>

#define TDIM 512
#define KDIM 8
#define DDIM 8
#define BDIM 2048

#define PSTRIDE 80   // per (t,k): rT[8][8] (row-major j,i), off[8], nc[8]
#define TT      8    // t values per block (one per wave)
#define BCHUNK  64   // b values per chunk (one per lane)
#define NCHUNK  4    // chunks per block -> 256 b per block
#define LDS_STRIDE 68

#ifndef __has_builtin
#define __has_builtin(x) 0
#endif
#if __has_builtin(__builtin_amdgcn_exp2f)
#define FAST_EXP2(x) __builtin_amdgcn_exp2f(x)
#else
#define FAST_EXP2(x) exp2f(x)
#endif

// ---------------- Precompute: per (t,k) rotation/scale params + softmax weights ----------
__global__ __launch_bounds__(256) void precompute_kernel(
    const float* __restrict__ centers,   // [T,K,8]
    const float* __restrict__ wlogits,   // [T,K]
    const float* __restrict__ logvar,    // [T,K,8]
    const float* __restrict__ covp,      // [T,K,28]
    float* __restrict__ P,               // [T*K*PSTRIDE]
    float* __restrict__ W)               // [T*K]
{
    int tid = blockIdx.x * blockDim.x + threadIdx.x;
    if (tid >= TDIM * KDIM) return;

    // --- build antisymmetric A from cov_param (replicates tf concat/reshape/mask) ---
    double v[28];
    const float* vp = covp + (size_t)tid * 28;
    #pragma unroll
    for (int n = 0; n < 28; n++) v[n] = (double)vp[n];

    auto flatval = [&](int n) -> double {
        if (n < 28) return v[n];
        if (n < 56) return v[55 - n];
        return 0.0;
    };

    double A[8][8];
    for (int i = 0; i < 8; i++)
        for (int j = 0; j < 8; j++) {
            double uij = (i < j) ? flatval(8 * i + j) : 0.0;
            double uji = (j < i) ? flatval(8 * j + i) : 0.0;
            A[i][j] = 0.5 * (uji - uij);
        }

    // --- invert (I + A) via Gauss-Jordan (no pivoting needed: sym part = I, PD) ---
    double M[8][16];
    for (int i = 0; i < 8; i++) {
        for (int j = 0; j < 8; j++) {
            M[i][j]     = A[i][j] + (i == j ? 1.0 : 0.0);
            M[i][8 + j] = (i == j) ? 1.0 : 0.0;
        }
    }
    for (int c = 0; c < 8; c++) {
        double piv = 1.0 / M[c][c];
        for (int j = 0; j < 16; j++) M[c][j] *= piv;
        for (int r = 0; r < 8; r++) {
            if (r == c) continue;
            double f = M[r][c];
            for (int j = 0; j < 16; j++) M[r][j] -= f * M[c][j];
        }
    }

    // --- q = (I - A) @ inv(I + A) ---
    double q[8][8];
    for (int i = 0; i < 8; i++)
        for (int j = 0; j < 8; j++) {
            double s = 0.0;
            for (int m = 0; m < 8; m++) {
                double im_a = (i == m ? 1.0 : 0.0) - A[i][m];
                s += im_a * M[m][8 + j];
            }
            q[i][j] = s;
        }

    // --- fold invstd, sqrt(0.5*log2e), center offsets, norm coeff ---
    const float* lvp = logvar  + (size_t)tid * 8;
    const float* cp  = centers + (size_t)tid * 8;
    float* pk = P + (size_t)tid * PSTRIDE;

    const double SQ    = 0.84932180028801904;   // sqrt(0.5 * log2(e))
    const double NORMC = 0.39894228040143268;   // 1/sqrt(2*pi)

    for (int j = 0; j < 8; j++) {
        double lv = (double)lvp[j];
        lv = fmin(fmax(lv, -3.5), 3.5);
        double invstd = exp(-0.5 * lv);
        double sc = invstd * SQ;
        double off = 0.0;
        for (int i = 0; i < 8; i++) {
            double r = q[i][j] * sc;
            pk[j * 8 + i] = (float)r;
            off += (double)cp[i] * r;
        }
        pk[64 + j] = (float)off;
        pk[72 + j] = (float)(NORMC * invstd);
    }

    // --- softmax of clipped weight_logits over K (groups of 8 lanes) ---
    float l = wlogits[tid];
    l = fminf(fmaxf(l, -3.5f), 3.5f);
    float m = l;
    for (int o = 4; o >= 1; o >>= 1) m = fmaxf(m, __shfl_xor(m, o, 8));
    float e = expf(l - m);
    float s = e;
    for (int o = 4; o >= 1; o >>= 1) s += __shfl_xor(s, o, 8);
    W[tid] = e / s;
}

// ---------------- Main kernel: one wave per t (wave-uniform params -> scalar loads) -----
__global__ __launch_bounds__(512, 4) void pecd_main_kernel(
    const float* __restrict__ x,   // [B,T,8]
    const float* __restrict__ P,   // [T*K*PSTRIDE]
    const float* __restrict__ W,   // [T*K]
    float* __restrict__ out)       // [B,T]
{
    __shared__ float xs[BCHUNK * LDS_STRIDE];

    const int t0     = (int)blockIdx.x * TT;                 // [0,512) step 8
    const int b_base = (int)blockIdx.y * (BCHUNK * NCHUNK);  // [0,2048) step 256
    const int wave   = threadIdx.x >> 6;
    const int lane   = threadIdx.x & 63;

    const int t  = t0 + wave;
    const int ts = __builtin_amdgcn_readfirstlane(t);        // wave-uniform -> scalar loads
    const float* __restrict__ Pt = P + (size_t)ts * (KDIM * PSTRIDE);
    const float* __restrict__ Wt = W + (size_t)ts * KDIM;

    for (int c = 0; c < NCHUNK; c++) {
        const int b0 = b_base + c * BCHUNK;

        __syncthreads();  // xs reuse across chunks
        // cooperative coalesced load: rows b0..b0+63, each row = x[b, t0:t0+8, :] (256 B)
        #pragma unroll
        for (int it = 0; it < 2; it++) {
            int idx = (int)threadIdx.x + it * 512;   // 0..1023 float4s
            int row = idx >> 4;
            int col = idx & 15;
            const float4* src =
                (const float4*)(x + ((size_t)(b0 + row) * TDIM + t0) * DDIM) + col;
            float4 val = *src;
            *(float4*)(xs + row * LDS_STRIDE + col * 4) = val;
        }
        __syncthreads();

        // each lane: one b, this wave's t
        const float* xr = xs + lane * LDS_STRIDE + wave * 8;
        float4 a0 = *(const float4*)(xr);
        float4 a1 = *(const float4*)(xr + 4);
        float xv[8] = {a0.x, a0.y, a0.z, a0.w, a1.x, a1.y, a1.z, a1.w};

        float acc = 0.0f;
        #pragma unroll
        for (int k = 0; k < KDIM; k++) {
            const float* pk = Pt + k * PSTRIDE;
            float prod = 1.0f;
            #pragma unroll
            for (int j = 0; j < 8; j++) {
                float u = -pk[64 + j];
                #pragma unroll
                for (int i = 0; i < 8; i++) u = fmaf(xv[i], pk[j * 8 + i], u);
                float e = FAST_EXP2(-(u * u));
                prod *= fmaf(pk[72 + j], e, 1e-7f);
            }
            acc = fmaf(Wt[k], prod, acc);
        }
        out[(size_t)(b0 + lane) * TDIM + t] = acc;
    }
}

extern "C" void kernel_launch(void* const* d_in, const int* in_sizes, int n_in,
                              void* d_out, int out_size, void* d_ws, size_t ws_size,
                              hipStream_t stream) {
    const float* x       = (const float*)d_in[0];  // [2048,512,8]
    const float* centers = (const float*)d_in[1];  // [512,8,8]
    const float* wlogits = (const float*)d_in[2];  // [512,8]
    const float* logvar  = (const float*)d_in[3];  // [512,8,8]
    const float* covp    = (const float*)d_in[4];  // [512,8,28]
    float* out = (float*)d_out;                    // [2048,512]

    float* P = (float*)d_ws;                       // 4096*80 floats
    float* W = P + (size_t)TDIM * KDIM * PSTRIDE;  // 4096 floats

    precompute_kernel<<<dim3((TDIM * KDIM + 255) / 256), dim3(256), 0, stream>>>(
        centers, wlogits, logvar, covp, P, W);

    dim3 grid(TDIM / TT, BDIM / (BCHUNK * NCHUNK));
    pecd_main_kernel<<<grid, dim3(512), 0, stream>>>(x, P, W, out);
}

// Round 2
// 108.514 us; speedup vs baseline: 3.1275x; 3.1275x over previous
//
#include <hip/hip_runtime.h>
#include <math.h>

#define TDIM 512
#define KDIM 8
#define DDIM 8
#define BDIM 2048

#define PSTRIDE 80   // per (t,k), j-major: j*10 + { rT_row[8], off, nc }

#ifndef __has_builtin
#define __has_builtin(x) 0
#endif
#if __has_builtin(__builtin_amdgcn_exp2f)
#define FAST_EXP2(x) __builtin_amdgcn_exp2f(x)
#else
#define FAST_EXP2(x) exp2f(x)
#endif

// ---------------- Precompute: per (t,k) rotation/scale params + softmax weights ----------
// q = (I-A)(I+A)^-1 = 2*(I+A)^-1 - I  -> only need in-place 8x8 f64 inversion (no spill).
__global__ __launch_bounds__(64) void precompute_kernel(
    const float* __restrict__ centers,   // [T,K,8]
    const float* __restrict__ wlogits,   // [T,K]
    const float* __restrict__ logvar,    // [T,K,8]
    const float* __restrict__ covp,      // [T,K,28]
    float* __restrict__ P,               // [T*K*PSTRIDE]
    float* __restrict__ W)               // [T*K]
{
    const int tid = blockIdx.x * 64 + threadIdx.x;   // 0..4095 = (t,k)

    float v[28];
    const float* vp = covp + (size_t)tid * 28;
    #pragma unroll
    for (int n = 0; n < 28; n++) v[n] = vp[n];

    // M = I + A, A antisym from tf concat/reshape/strict-upper mask.
    // UT[i][j] (i<j) = flat(8i+j), flat(n) = v[n] (n<28) | v[55-n] (n<56).
    // A = 0.5*(UT^T - UT).
    double M[8][8];
    #pragma unroll
    for (int i = 0; i < 8; i++) {
        #pragma unroll
        for (int j = 0; j < 8; j++) {
            double a;
            if (i == j) {
                a = 0.0;
            } else if (i < j) {
                const int n = 8 * i + j;
                a = -0.5 * (double)((n < 28) ? v[n] : v[55 - n]);
            } else {
                const int n = 8 * j + i;
                a = 0.5 * (double)((n < 28) ? v[n] : v[55 - n]);
            }
            M[i][j] = (i == j ? 1.0 : 0.0) + a;
        }
    }

    // In-place Gauss-Jordan inversion (no pivoting: principal minors of I+A are >= 1).
    #pragma unroll
    for (int c = 0; c < 8; c++) {
        const double p = 1.0 / M[c][c];
        M[c][c] = 1.0;
        #pragma unroll
        for (int j = 0; j < 8; j++) M[c][j] *= p;
        #pragma unroll
        for (int r = 0; r < 8; r++) {
            if (r == c) continue;
            const double f = M[r][c];
            M[r][c] = 0.0;
            #pragma unroll
            for (int j = 0; j < 8; j++) M[r][j] = fma(-f, M[c][j], M[r][j]);
        }
    }
    // q[i][j] = 2*M[i][j] - delta_ij

    const float* lvp = logvar  + (size_t)tid * 8;
    const float* cp  = centers + (size_t)tid * 8;
    float* pk = P + (size_t)tid * PSTRIDE;

    const double SQ    = 0.84932180028801904;   // sqrt(0.5 * log2(e))
    const double NORMC = 0.39894228040143268;   // 1/sqrt(2*pi)

    #pragma unroll
    for (int j = 0; j < 8; j++) {
        double lv = (double)lvp[j];
        lv = fmin(fmax(lv, -3.5), 3.5);
        const double invstd = exp(-0.5 * lv);
        const double sc = invstd * SQ;
        double off = 0.0;
        #pragma unroll
        for (int i = 0; i < 8; i++) {
            const double q = 2.0 * M[i][j] - (i == j ? 1.0 : 0.0);
            const double r = q * sc;
            pk[j * 10 + i] = (float)r;
            off += (double)cp[i] * r;
        }
        pk[j * 10 + 8] = (float)off;
        pk[j * 10 + 9] = (float)(NORMC * invstd);
    }

    // softmax of clipped weight_logits over K (groups of 8 lanes, k = tid & 7)
    float l = wlogits[tid];
    l = fminf(fmaxf(l, -3.5f), 3.5f);
    float m = l;
    for (int o = 4; o >= 1; o >>= 1) m = fmaxf(m, __shfl_xor(m, o, 8));
    const float e = expf(l - m);
    float s = e;
    for (int o = 4; o >= 1; o >>= 1) s += __shfl_xor(s, o, 8);
    W[tid] = e / s;
}

// ---------------- Main kernel: wave<->t (uniform params -> scalar loads), 4-b blocking --
__global__ __launch_bounds__(512, 4) void pecd_main_kernel(
    const float* __restrict__ x,   // [B,T,8]
    const float* __restrict__ P,   // [T*K*PSTRIDE]
    const float* __restrict__ W,   // [T*K]
    float* __restrict__ out)       // [B,T]
{
    __shared__ float xs[64 * 68];

    const int t0     = (int)blockIdx.x * 8;     // wave w handles t0+w
    const int b_base = (int)blockIdx.y * 256;   // 4 chunks of 64 b
    const int wave   = threadIdx.x >> 6;
    const int lane   = threadIdx.x & 63;

    const int t  = t0 + wave;
    const int ts = __builtin_amdgcn_readfirstlane(t);   // wave-uniform -> s_load params
    const float* __restrict__ Pt = P + (size_t)ts * (KDIM * PSTRIDE);
    const float* __restrict__ Wt = W + (size_t)ts * KDIM;

    // Stage x through LDS (coalesced), keep 4 b-rows per lane in registers.
    float xv[4][8];
    #pragma unroll
    for (int c = 0; c < 4; c++) {
        const int b0 = b_base + c * 64;
        __syncthreads();
        #pragma unroll
        for (int it = 0; it < 2; it++) {
            const int idx = (int)threadIdx.x + it * 512;   // 0..1023 float4s
            const int row = idx >> 4;
            const int col = idx & 15;
            const float4 val =
                *((const float4*)(x + ((size_t)(b0 + row) * TDIM + t0) * DDIM) + col);
            *(float4*)(xs + row * 68 + col * 4) = val;
        }
        __syncthreads();
        const float* xr = xs + lane * 68 + wave * 8;
        const float4 a0 = *(const float4*)(xr);
        const float4 a1 = *(const float4*)(xr + 4);
        xv[c][0] = a0.x; xv[c][1] = a0.y; xv[c][2] = a0.z; xv[c][3] = a0.w;
        xv[c][4] = a1.x; xv[c][5] = a1.y; xv[c][6] = a1.z; xv[c][7] = a1.w;
    }

    float acc[4] = {0.f, 0.f, 0.f, 0.f};
    #pragma unroll 1
    for (int k = 0; k < KDIM; k++) {
        const float* pk = Pt + k * PSTRIDE;
        const float wk = Wt[k];
        float prod[4] = {1.f, 1.f, 1.f, 1.f};
        #pragma unroll
        for (int j = 0; j < 8; j++) {
            float rr[10];
            #pragma unroll
            for (int q = 0; q < 10; q++) rr[q] = pk[j * 10 + q];
            #pragma unroll
            for (int c = 0; c < 4; c++) {
                float u = -rr[8];
                #pragma unroll
                for (int i = 0; i < 8; i++) u = fmaf(xv[c][i], rr[i], u);
                const float e = FAST_EXP2(-(u * u));
                prod[c] *= fmaf(rr[9], e, 1e-7f);
            }
        }
        #pragma unroll
        for (int c = 0; c < 4; c++) acc[c] = fmaf(wk, prod[c], acc[c]);
    }

    #pragma unroll
    for (int c = 0; c < 4; c++)
        out[(size_t)(b_base + c * 64 + lane) * TDIM + t] = acc[c];
}

extern "C" void kernel_launch(void* const* d_in, const int* in_sizes, int n_in,
                              void* d_out, int out_size, void* d_ws, size_t ws_size,
                              hipStream_t stream) {
    const float* x       = (const float*)d_in[0];  // [2048,512,8]
    const float* centers = (const float*)d_in[1];  // [512,8,8]
    const float* wlogits = (const float*)d_in[2];  // [512,8]
    const float* logvar  = (const float*)d_in[3];  // [512,8,8]
    const float* covp    = (const float*)d_in[4];  // [512,8,28]
    float* out = (float*)d_out;                    // [2048,512]

    float* P = (float*)d_ws;                       // 4096*80 floats
    float* W = P + (size_t)TDIM * KDIM * PSTRIDE;  // 4096 floats

    precompute_kernel<<<dim3(64), dim3(64), 0, stream>>>(
        centers, wlogits, logvar, covp, P, W);

    dim3 grid(TDIM / 8, BDIM / 256);
    pecd_main_kernel<<<grid, dim3(512), 0, stream>>>(x, P, W, out);
}

// Round 4
// 104.000 us; speedup vs baseline: 3.2632x; 1.0434x over previous
//
#include <hip/hip_runtime.h>
#include <math.h>

#define TDIM 512
#define KDIM 8
#define DDIM 8
#define BDIM 2048
#define EPSF 1e-7f

#ifndef __has_builtin
#define __has_builtin(x) 0
#endif
#if __has_builtin(__builtin_amdgcn_exp2f)
#define FAST_EXP2(x) __builtin_amdgcn_exp2f(x)
#else
#define FAST_EXP2(x) exp2f(x)
#endif

// Single fused kernel.
// Phase A: 8-lane-parallel f32 in-place Gauss-Jordan Cayley precompute for this
//          block's 8 t's x 8 k's -> params in LDS. (I+A with A antisymmetric =>
//          all pivots >= 1, no pivoting needed; cond(I+A) ~ 3 so f32 is safe.)
//          NOTE: in-place inversion accumulates the inverse through the pivot
//          COLUMN: row c's col-c entry := pinv, row r's col-c entry := -f*pinv.
// Phase B: per-wave t (uniform LDS param reads -> broadcast), 4-b register
//          blocking, x staged via coalesced float4 -> LDS -> registers.
__global__ __launch_bounds__(512, 4) void pecd_fused(
    const float* __restrict__ x,         // [B,T,8]
    const float* __restrict__ centers,   // [T,K,8]
    const float* __restrict__ wlogits,   // [T,K]
    const float* __restrict__ logvar,    // [T,K,8]
    const float* __restrict__ covp,      // [T,K,28]
    float* __restrict__ out)             // [B,T]
{
    // params per tk (80 floats): [j*8+i] = rT[j][i] = q[i][j]*sc_j ;
    //                            [64+j] = off_j ; [72+j] = nc_j
    __shared__ float prm[64 * 80];   // 20 KB
    __shared__ float Wl[64];
    __shared__ float xs[64 * 68];    // 17 KB staging

    const int tidx   = (int)threadIdx.x;
    const int t0     = (int)blockIdx.x * 8;     // wave w handles t0+w
    const int b_base = (int)blockIdx.y * 256;   // 4 chunks of 64 b

    // ================= Phase A: parameter precompute =================
    {
        const int tk = tidx >> 3;                 // 0..63 : (t_local, k)
        const int r  = tidx & 7;                  // row of the 8x8 system
        const int kk = tk & 7;
        const int tl = tk >> 3;                   // == wave id
        const size_t tkg = (size_t)(t0 + tl) * 8 + kk;

        // row r of M = I + A ; A = 0.5*(UT^T - UT), UT strict-upper from
        // flat(n) = v[n] (n<28) | v[55-n] (28<=n<56), n = 8*min+max.
        const float* cb = covp + tkg * 28;
        float row[8];
        #pragma unroll
        for (int j = 0; j < 8; j++) {
            const int lo = (r < j) ? r : j;
            const int hi = (r < j) ? j : r;
            const int n  = 8 * lo + hi;
            const int m  = (r == j) ? 0 : ((n < 28) ? n : 55 - n);
            const float v = cb[m];
            const float a = (r < j) ? -0.5f * v : 0.5f * v;
            row[j] = (r == j) ? 1.0f : a;
        }

        // In-place Gauss-Jordan inversion, row-parallel across 8 lanes.
        #pragma unroll
        for (int c = 0; c < 8; c++) {
            float prow[8];
            #pragma unroll
            for (int j = 0; j < 8; j++) prow[j] = __shfl(row[j], c, 8);
            const float pinv = 1.0f / prow[c];
            const float f = row[c];   // my row's col-c entry (before update)
            #pragma unroll
            for (int j = 0; j < 8; j++) {
                if (j == c) {
                    // pivot COLUMN: inverse accumulates here (in-place trick)
                    row[j] = (r == c) ? pinv : -f * pinv;
                } else {
                    const float spiv = prow[j] * pinv;
                    row[j] = (r == c) ? spiv : fmaf(-f, spiv, row[j]);
                }
            }
        }
        // row[] now = inv(I+A)[r][*] ; q[r][j] = 2*row[j] - (r==j)

        const float* lvp = logvar + tkg * 8;
        float invstd[8];
        #pragma unroll
        for (int j = 0; j < 8; j++) {
            const float lv = fminf(fmaxf(lvp[j], -3.5f), 3.5f);
            invstd[j] = exp2f(lv * -0.7213475204444817f);  // exp(-lv/2)
        }
        const float cr = centers[tkg * 8 + r];
        float* pp = prm + tk * 80;
        float offp[8];
        #pragma unroll
        for (int j = 0; j < 8; j++) {
            const float q = 2.0f * row[j] - (r == j ? 1.0f : 0.0f);
            const float val = q * (invstd[j] * 0.8493218002880191f); // sqrt(0.5*log2e)
            pp[j * 8 + r] = val;
            offp[j] = cr * val;
        }
        #pragma unroll
        for (int j = 0; j < 8; j++) {
            offp[j] += __shfl_xor(offp[j], 1, 8);
            offp[j] += __shfl_xor(offp[j], 2, 8);
            offp[j] += __shfl_xor(offp[j], 4, 8);
        }
        if (r == 0) {
            #pragma unroll
            for (int j = 0; j < 8; j++) {
                pp[64 + j] = offp[j];
                pp[72 + j] = 0.3989422804014327f * invstd[j];  // 1/sqrt(2pi)*invstd
            }
        }

        // softmax over k: k lives in lane bits 3..5 within the wave.
        float l = fminf(fmaxf(wlogits[tkg], -3.5f), 3.5f);
        float mx = l;
        mx = fmaxf(mx, __shfl_xor(mx, 8, 64));
        mx = fmaxf(mx, __shfl_xor(mx, 16, 64));
        mx = fmaxf(mx, __shfl_xor(mx, 32, 64));
        const float e = exp2f((l - mx) * 1.4426950408889634f);
        float ss = e;
        ss += __shfl_xor(ss, 8, 64);
        ss += __shfl_xor(ss, 16, 64);
        ss += __shfl_xor(ss, 32, 64);
        if (r == 0) Wl[tk] = e / ss;
    }

    // ================= Phase B: main evaluation =================
    const int wave = tidx >> 6;
    const int lane = tidx & 63;

    float xv[4][8];
    #pragma unroll
    for (int c = 0; c < 4; c++) {
        const int b0 = b_base + c * 64;
        __syncthreads();   // (also orders Phase A prm writes before first use)
        #pragma unroll
        for (int it = 0; it < 2; it++) {
            const int idx  = tidx + it * 512;    // 0..1023 float4s
            const int brow = idx >> 4;
            const int col  = idx & 15;
            const float4 val =
                *((const float4*)(x + ((size_t)(b0 + brow) * TDIM + t0) * DDIM) + col);
            *(float4*)(xs + brow * 68 + col * 4) = val;
        }
        __syncthreads();
        const float* xr = xs + lane * 68 + wave * 8;
        const float4 a0 = *(const float4*)(xr);
        const float4 a1 = *(const float4*)(xr + 4);
        xv[c][0] = a0.x; xv[c][1] = a0.y; xv[c][2] = a0.z; xv[c][3] = a0.w;
        xv[c][4] = a1.x; xv[c][5] = a1.y; xv[c][6] = a1.z; xv[c][7] = a1.w;
    }

    const float* pw = prm + wave * (8 * 80);
    float acc[4] = {0.f, 0.f, 0.f, 0.f};
    #pragma unroll 1
    for (int k = 0; k < KDIM; k++) {
        const float* pk = pw + k * 80;
        float off[8], nc[8];
        *(float4*)&off[0] = *(const float4*)(pk + 64);
        *(float4*)&off[4] = *(const float4*)(pk + 68);
        *(float4*)&nc[0]  = *(const float4*)(pk + 72);
        *(float4*)&nc[4]  = *(const float4*)(pk + 76);
        const float wk = Wl[wave * 8 + k];
        float prod[4] = {1.f, 1.f, 1.f, 1.f};
        #pragma unroll
        for (int j = 0; j < 8; j++) {
            float rr[8];
            *(float4*)&rr[0] = *(const float4*)(pk + j * 8);
            *(float4*)&rr[4] = *(const float4*)(pk + j * 8 + 4);
            #pragma unroll
            for (int c = 0; c < 4; c++) {
                float u = -off[j];
                #pragma unroll
                for (int i = 0; i < 8; i++) u = fmaf(xv[c][i], rr[i], u);
                const float e2 = FAST_EXP2(-(u * u));
                prod[c] *= fmaf(nc[j], e2, EPSF);
            }
        }
        #pragma unroll
        for (int c = 0; c < 4; c++) acc[c] = fmaf(wk, prod[c], acc[c]);
    }

    #pragma unroll
    for (int c = 0; c < 4; c++)
        out[(size_t)(b_base + c * 64 + lane) * TDIM + (t0 + wave)] = acc[c];
}

extern "C" void kernel_launch(void* const* d_in, const int* in_sizes, int n_in,
                              void* d_out, int out_size, void* d_ws, size_t ws_size,
                              hipStream_t stream) {
    const float* x       = (const float*)d_in[0];  // [2048,512,8]
    const float* centers = (const float*)d_in[1];  // [512,8,8]
    const float* wlogits = (const float*)d_in[2];  // [512,8]
    const float* logvar  = (const float*)d_in[3];  // [512,8,8]
    const float* covp    = (const float*)d_in[4];  // [512,8,28]
    float* out = (float*)d_out;                    // [2048,512]
    (void)d_ws; (void)ws_size;

    dim3 grid(TDIM / 8, BDIM / 256);
    pecd_fused<<<grid, dim3(512), 0, stream>>>(x, centers, wlogits, logvar, covp, out);
}

// Round 5
// 100.401 us; speedup vs baseline: 3.3802x; 1.0358x over previous
//
#include <hip/hip_runtime.h>
#include <math.h>

#define TDIM 512
#define KDIM 8
#define DDIM 8
#define BDIM 2048

#define PSTRIDE 76   // per (t,k): rT[j*8+i] (64), off[8], slc, pad[3]

#ifndef __has_builtin
#define __has_builtin(x) 0
#endif
#if __has_builtin(__builtin_amdgcn_exp2f)
#define FAST_EXP2(x) __builtin_amdgcn_exp2f(x)
#else
#define FAST_EXP2(x) exp2f(x)
#endif

// ---------------- Precompute: 8-lane-parallel f32 Cayley + folded constants ----------
// Per (t,k) writes: rT[j][i] = q[i][j]*invstd_j*sqrt(0.5*log2e)  (so u_j = x.rT_j - off_j
// and gaussian_j = nc_j * 2^(-u_j^2)); off_j = c . rT_j;
// slc = log2(w_k) + sum_j log2(nc_j)  (EPS dropped: p_k = 2^(slc - sum_j u_j^2)).
__global__ __launch_bounds__(512) void precompute_kernel(
    const float* __restrict__ centers,   // [T,K,8]
    const float* __restrict__ wlogits,   // [T,K]
    const float* __restrict__ logvar,    // [T,K,8]
    const float* __restrict__ covp,      // [T,K,28]
    float* __restrict__ P)               // [T*K*PSTRIDE]
{
    const int tid = (int)blockIdx.x * 512 + (int)threadIdx.x;
    const int tk  = tid >> 3;            // 0..4095 = (t,k)
    const int r   = tid & 7;             // row of the 8x8 system
    const size_t tkg = (size_t)tk;

    // row r of M = I + A ; A = 0.5*(UT^T - UT), UT strict-upper from
    // flat(n) = v[n] (n<28) | v[55-n] (28<=n<56), n = 8*min+max.
    const float* cb = covp + tkg * 28;
    float row[8];
    #pragma unroll
    for (int j = 0; j < 8; j++) {
        const int lo = (r < j) ? r : j;
        const int hi = (r < j) ? j : r;
        const int n  = 8 * lo + hi;
        const int m  = (r == j) ? 0 : ((n < 28) ? n : 55 - n);
        const float v = cb[m];
        const float a = (r < j) ? -0.5f * v : 0.5f * v;
        row[j] = (r == j) ? 1.0f : a;
    }

    // In-place Gauss-Jordan inversion, row-parallel across 8 lanes.
    // (inverse accumulates through the pivot COLUMN — verified round 4)
    #pragma unroll
    for (int c = 0; c < 8; c++) {
        float prow[8];
        #pragma unroll
        for (int j = 0; j < 8; j++) prow[j] = __shfl(row[j], c, 8);
        const float pinv = 1.0f / prow[c];
        const float f = row[c];
        #pragma unroll
        for (int j = 0; j < 8; j++) {
            if (j == c) {
                row[j] = (r == c) ? pinv : -f * pinv;
            } else {
                const float spiv = prow[j] * pinv;
                row[j] = (r == c) ? spiv : fmaf(-f, spiv, row[j]);
            }
        }
    }
    // row[] = inv(I+A)[r][*] ; q[r][j] = 2*row[j] - (r==j)

    const float* lvp = logvar + tkg * 8;
    float invstd[8];
    float sumlv = 0.0f;
    #pragma unroll
    for (int j = 0; j < 8; j++) {
        const float lv = fminf(fmaxf(lvp[j], -3.5f), 3.5f);
        sumlv += lv;
        invstd[j] = exp2f(lv * -0.7213475204444817f);  // exp(-lv/2)
    }
    const float cr = centers[tkg * 8 + r];
    float* pp = P + tkg * PSTRIDE;
    float offp[8];
    #pragma unroll
    for (int j = 0; j < 8; j++) {
        const float q = 2.0f * row[j] - (r == j ? 1.0f : 0.0f);
        const float val = q * (invstd[j] * 0.8493218002880191f); // sqrt(0.5*log2e)
        pp[j * 8 + r] = val;
        offp[j] = cr * val;
    }
    #pragma unroll
    for (int j = 0; j < 8; j++) {
        offp[j] += __shfl_xor(offp[j], 1, 8);
        offp[j] += __shfl_xor(offp[j], 2, 8);
        offp[j] += __shfl_xor(offp[j], 4, 8);
    }

    // softmax over k (k = lane bits 3..5) -> log2(w) directly
    float l = fminf(fmaxf(wlogits[tkg], -3.5f), 3.5f);
    float mx = l;
    mx = fmaxf(mx, __shfl_xor(mx, 8, 64));
    mx = fmaxf(mx, __shfl_xor(mx, 16, 64));
    mx = fmaxf(mx, __shfl_xor(mx, 32, 64));
    const float e = exp2f((l - mx) * 1.4426950408889634f);
    float ss = e;
    ss += __shfl_xor(ss, 8, 64);
    ss += __shfl_xor(ss, 16, 64);
    ss += __shfl_xor(ss, 32, 64);
    const float log2w = (l - mx) * 1.4426950408889634f - log2f(ss);

    if (r == 0) {
        #pragma unroll
        for (int j = 0; j < 8; j++) pp[64 + j] = offp[j];
        // sum_j log2(nc_j) = 8*log2(1/sqrt(2pi)) - log2e/2 * sum_j lv_j
        pp[72] = log2w - 10.605984517349169f - 0.7213475204444817f * sumlv;
    }
}

// ---------------- Main: lane<->b, wave<->2 t's, s_load params, coalesced stores --------
__global__ __launch_bounds__(512, 6) void pecd_main(
    const float* __restrict__ x,   // [B,T,8]
    const float* __restrict__ P,   // [T*K*PSTRIDE]
    float* __restrict__ out)       // [B,T]
{
    __shared__ float os[64 * 18];  // 4.6 KB transpose buffer (stride 18: 8B-aligned rows)

    const int tidx = (int)threadIdx.x;
    const int wv   = tidx >> 6;
    const int ln   = tidx & 63;
    const int t0   = (int)blockIdx.x * 16;   // t-tile 16
    const int b0   = (int)blockIdx.y * 64;   // b-tile 64 (lane<->b)

    const float* xb = x + ((size_t)(b0 + ln) * TDIM + t0) * DDIM;

    #pragma unroll
    for (int tt = 0; tt < 2; tt++) {
        const int tl = wv * 2 + tt;          // local t 0..15 (wave-uniform)
        const int ts = __builtin_amdgcn_readfirstlane(t0 + tl);
        const float* __restrict__ pt = P + (size_t)ts * (KDIM * PSTRIDE);

        const float4 a0 = *(const float4*)(xb + tl * 8);
        const float4 a1 = *(const float4*)(xb + tl * 8 + 4);
        const float xv[8] = {a0.x, a0.y, a0.z, a0.w, a1.x, a1.y, a1.z, a1.w};

        float acc = 0.0f;
        #pragma unroll 1
        for (int k = 0; k < KDIM; k++) {
            const float* pk = pt + k * PSTRIDE;   // wave-uniform -> s_loads
            float s0 = 0.0f, s1 = 0.0f;
            #pragma unroll
            for (int j = 0; j < 8; j++) {
                float u = -pk[64 + j];
                #pragma unroll
                for (int i = 0; i < 8; i++) u = fmaf(xv[i], pk[j * 8 + i], u);
                if (j & 1) s1 = fmaf(u, u, s1);
                else       s0 = fmaf(u, u, s0);
            }
            acc += FAST_EXP2(pk[72] - s0 - s1);
        }
        os[ln * 18 + tl] = acc;
    }
    __syncthreads();

    // cooperative coalesced store: row = b, 16 t's = 64 B contiguous
    {
        const int row = tidx >> 3;       // 0..63
        const int col = tidx & 7;        // 0..7 -> float2
        const float2 v = *(const float2*)&os[row * 18 + col * 2];
        *(float2*)(out + (size_t)(b0 + row) * TDIM + t0 + col * 2) = v;
    }
}

extern "C" void kernel_launch(void* const* d_in, const int* in_sizes, int n_in,
                              void* d_out, int out_size, void* d_ws, size_t ws_size,
                              hipStream_t stream) {
    const float* x       = (const float*)d_in[0];  // [2048,512,8]
    const float* centers = (const float*)d_in[1];  // [512,8,8]
    const float* wlogits = (const float*)d_in[2];  // [512,8]
    const float* logvar  = (const float*)d_in[3];  // [512,8,8]
    const float* covp    = (const float*)d_in[4];  // [512,8,28]
    float* out = (float*)d_out;                    // [2048,512]

    float* P = (float*)d_ws;                       // 4096*76 floats = 1.24 MB

    precompute_kernel<<<dim3(TDIM * KDIM * 8 / 512), dim3(512), 0, stream>>>(
        centers, wlogits, logvar, covp, P);

    dim3 grid(TDIM / 16, BDIM / 64);               // (32, 32) = 1024 blocks
    pecd_main<<<grid, dim3(512), 0, stream>>>(x, P, out);
}